// Round 4
// baseline (2164.958 us; speedup 1.0000x reference)
//
#include <hip/hip_runtime.h>

#define FIN   64
#define FOUT  64
#define HI    128
#define WI    128
#define HO    126
#define WO    126
#define TH    16      // tile rows
#define TW    32      // tile cols
#define OCH   16      // output channels per block
#define ISPL  2       // input-channel split across blocks
#define ICH   (FIN/ISPL)   // 32 channels per block
#define HR    (TH+2)
#define HC    (TW+2)
#define LSTR  36      // padded LDS row stride
#define NSTAGE 3      // ceil(HR*HC/256) = ceil(612/256)
#define WSLOT 12      // 9 Wf + bf + Wc + pad  (48B -> 3x b128-aligned)
#define NW    22      // ICH*OCH*11 / 256 = 5632/256

__global__ __launch_bounds__(256, 4) void fused_dwconv_combine(
    const float* __restrict__ x,  const float* __restrict__ Wf,
    const float* __restrict__ bf, const float* __restrict__ Wc,
    const float* __restrict__ bc, float* __restrict__ out)
{
    __shared__ float xs[2][HR * LSTR];          // 5.2 KB
    __shared__ float wlds[ICH][OCH][WSLOT];     // 24 KB

    const int tid = threadIdx.x;
    const int tx  = tid & 15;          // cols 2tx, 2tx+1
    const int ty  = tid >> 4;          // row
    const int tY  = blockIdx.x >> 2;   // 0..7
    const int tX  = blockIdx.x & 3;    // 0..3
    const int oc  = blockIdx.y >> 1;   // 0..3 o-chunk
    const int ih  = blockIdx.y & 1;    // i-half
    const int o0  = oc * OCH;
    const int i0  = ih * ICH;
    const int b   = blockIdx.z;

    const int row0 = tY * TH;
    const int col0 = tX * TW;

    // ---- stage weights for this (o-chunk, i-half) into LDS: in-order DS
    // reads later, no SMEM out-of-order lgkm drains in the hot loop ----
#pragma unroll
    for (int k = 0; k < NW; ++k) {
        int e  = tid + k * 256;              // 0..5631
        int il = e / (OCH * 11);
        int r  = e - il * (OCH * 11);
        int oo = r / 11;
        int t  = r - oo * 11;
        int o  = o0 + oo, i = i0 + il;
        float v = (t < 9) ? Wf[((size_t)o * FIN + i) * 9 + t]
                          : (t == 9 ? bf[o * FIN + i] : Wc[o * FIN + i]);
        wlds[il][oo][t] = v;
    }

    // ---- x staging map (computed once) ----
    int goff[NSTAGE], loff[NSTAGE];
#pragma unroll
    for (int k = 0; k < NSTAGE; ++k) {
        int e = tid + k * 256;
        if (e < HR * HC) {
            int r = e / HC, c = e - r * HC;
            int gy = min(row0 + r, HI - 1);
            int gx = min(col0 + c, WI - 1);
            goff[k] = gy * WI + gx;
            loff[k] = r * LSTR + c;
        } else { goff[k] = 0; loff[k] = -1; }
    }

    const float* xb = x + ((size_t)b * FIN + i0) * (HI * WI);

    float acc[OCH][2];
#pragma unroll
    for (int oo = 0; oo < OCH; ++oo) {
        float bcv = (ih == 0) ? bc[o0 + oo] : 0.0f;   // bias exactly once
        acc[oo][0] = bcv; acc[oo][1] = bcv;
    }

    // stage channel i0 into buffer 0
#pragma unroll
    for (int k = 0; k < NSTAGE; ++k)
        if (loff[k] >= 0) xs[0][loff[k]] = xb[goff[k]];

    auto body = [&](int il, int cur) {
        float st[NSTAGE];
        if (il + 1 < ICH) {
            const float* xp = xb + (size_t)(il + 1) * (HI * WI);
#pragma unroll
            for (int k = 0; k < NSTAGE; ++k)
                if (loff[k] >= 0) st[k] = xp[goff[k]];
        }

        __syncthreads();   // xs[cur] committed; previous reads complete

        // 3x4 window: 6 aligned ds_read_b64
        float w00, w01, w02, w03, w10, w11, w12, w13, w20, w21, w22, w23;
        {
            const float* r0 = &xs[cur][(ty + 0) * LSTR + 2 * tx];
            const float* r1 = &xs[cur][(ty + 1) * LSTR + 2 * tx];
            const float* r2 = &xs[cur][(ty + 2) * LSTR + 2 * tx];
            w00 = r0[0]; w01 = r0[1]; w02 = r0[2]; w03 = r0[3];
            w10 = r1[0]; w11 = r1[1]; w12 = r1[2]; w13 = r1[3];
            w20 = r2[0]; w21 = r2[1]; w22 = r2[2]; w23 = r2[3];
        }

#pragma unroll
        for (int oo = 0; oo < OCH; ++oo) {
            const float* wq = &wlds[il][oo][0];   // broadcast ds_read_b128 x3
            const float bfv = wq[9];
            const float wcv = wq[10];
            float s0 = bfv, s1 = bfv;
            s0 = fmaf(wq[0], w00, s0);  s1 = fmaf(wq[0], w01, s1);
            s0 = fmaf(wq[1], w01, s0);  s1 = fmaf(wq[1], w02, s1);
            s0 = fmaf(wq[2], w02, s0);  s1 = fmaf(wq[2], w03, s1);
            s0 = fmaf(wq[3], w10, s0);  s1 = fmaf(wq[3], w11, s1);
            s0 = fmaf(wq[4], w11, s0);  s1 = fmaf(wq[4], w12, s1);
            s0 = fmaf(wq[5], w12, s0);  s1 = fmaf(wq[5], w13, s1);
            s0 = fmaf(wq[6], w20, s0);  s1 = fmaf(wq[6], w21, s1);
            s0 = fmaf(wq[7], w21, s0);  s1 = fmaf(wq[7], w22, s1);
            s0 = fmaf(wq[8], w22, s0);  s1 = fmaf(wq[8], w23, s1);
            acc[oo][0] = fmaf(wcv, fmaxf(s0, 0.f), acc[oo][0]);
            acc[oo][1] = fmaf(wcv, fmaxf(s1, 0.f), acc[oo][1]);
        }

        if (il + 1 < ICH) {
#pragma unroll
            for (int k = 0; k < NSTAGE; ++k)
                if (loff[k] >= 0) xs[cur ^ 1][loff[k]] = st[k];
        }
    };

    for (int ii = 0; ii < ICH; ii += 2) {   // static buffer parity
        body(ii + 0, 0);
        body(ii + 1, 1);
    }

    // ---- epilogue: accumulate the two i-halves via exact fp32 atomics ----
    const int ho  = row0 + ty;
    const int wo0 = col0 + 2 * tx;
    if (ho < HO) {
#pragma unroll
        for (int oo = 0; oo < OCH; ++oo) {
            size_t base = ((size_t)b * FOUT + (o0 + oo)) * (size_t)(HO * WO)
                        + (size_t)ho * WO + wo0;
            if (wo0 + 0 < WO) unsafeAtomicAdd(&out[base + 0], acc[oo][0]);
            if (wo0 + 1 < WO) unsafeAtomicAdd(&out[base + 1], acc[oo][1]);
        }
    }
}

extern "C" void kernel_launch(void* const* d_in, const int* in_sizes, int n_in,
                              void* d_out, int out_size, void* d_ws, size_t ws_size,
                              hipStream_t stream) {
    const float* x  = (const float*)d_in[0];
    const float* Wf = (const float*)d_in[1];
    const float* bf = (const float*)d_in[2];
    const float* Wc = (const float*)d_in[3];
    const float* bc = (const float*)d_in[4];
    float* out = (float*)d_out;

    // zero the output (atomic accumulation base; exact & deterministic)
    hipMemsetAsync(out, 0, (size_t)out_size * sizeof(float), stream);

    dim3 grid(32, (FOUT / OCH) * ISPL, 4);   // 8x4 tiles, 4 o-chunks x 2 i-halves, 4 b
    hipLaunchKernelGGL(fused_dwconv_combine, grid, dim3(256), 0, stream,
                       x, Wf, bf, Wc, bc, out);
}

// Round 6
// 58.381 us; speedup vs baseline: 37.0830x; 37.0830x over previous
//
#include <hip/hip_runtime.h>

typedef _Float16 f16;
typedef f16 f16x4 __attribute__((ext_vector_type(4)));
typedef f16 f16x8 __attribute__((ext_vector_type(8)));
typedef float f32x4 __attribute__((ext_vector_type(4)));
typedef float f32x16 __attribute__((ext_vector_type(16)));

#define FIN  64
#define FOUT 64
#define HI   128
#define WI   128
#define HO   126
#define WO   126

// ws layout: A-fragment table f16 [i][ob][lane][8] = 64*2*64*16B = 128 KiB
//            Wc f32 table [i][o] = 16 KiB at byte offset 131072  (147,456 B total)
// k-labeling (same map used for A-table build and B-assembly; HW applies the
// same (g,j)->k map to both operands, so any consistent labeling is valid):
//   k = g*4 + (j&3) + 8*(j>>2),  g = lane>>5, j = 0..7
//   taps: k=4*dy+dx (dx<3 real, dx=3 zero-pad), k12 = bias slot (B=1), k13..15 = 0

__global__ __launch_bounds__(256) void prepass(
    const float* __restrict__ Wf, const float* __restrict__ bf,
    const float* __restrict__ Wc, unsigned short* __restrict__ ws)
{
    int t = blockIdx.x * 256 + threadIdx.x;
    if (t < 8192) {                      // A entries: t = (i*2+ob)*64 + l
        int i  = t >> 7;
        int ob = (t >> 6) & 1;
        int l  = t & 63;
        int g  = l >> 5, m = l & 31;
        int o  = ob * 32 + m;
        unsigned short h[8];
#pragma unroll
        for (int j = 0; j < 8; ++j) {
            int k = g * 4 + (j & 3) + 8 * (j >> 2);
            float v = 0.0f;
            if (k < 12) {
                int dy = k >> 2, dx = k & 3;
                if (dx < 3) v = Wf[((size_t)o * FIN + i) * 9 + dy * 3 + dx];
            } else if (k == 12) {
                v = bf[o * FIN + i];
            }
            f16 hv = (f16)v;
            h[j] = *(unsigned short*)&hv;
        }
        uint4 pk;
        pk.x = h[0] | ((unsigned)h[1] << 16);
        pk.y = h[2] | ((unsigned)h[3] << 16);
        pk.z = h[4] | ((unsigned)h[5] << 16);
        pk.w = h[6] | ((unsigned)h[7] << 16);
        *(uint4*)&ws[(size_t)t * 8] = pk;
    } else if (t < 8192 + 4096) {        // Wc f32 table: [i][o] = Wc[o][i]
        int t2 = t - 8192;
        int i = t2 >> 6, o = t2 & 63;
        float* wcf = (float*)(ws + 65536);   // byte offset 131072
        wcf[t2] = Wc[o * FIN + i];
    }
}

__global__ __launch_bounds__(256, 2) void conv_mfma(
    const float* __restrict__ x, const float* __restrict__ bc,
    const unsigned short* __restrict__ ws, float* __restrict__ out)
{
    // x tile: 18 halo rows x 8 col-slots (each slot = 4 f16 window cols), pad to 9
    __shared__ f16 xsl[2][18][9][4];     // 2.6 KB
    __shared__ float wcl[FIN][FOUT];     // 16 KB, [i][o], f32
    __shared__ __align__(8) f16 onev[4];

    const int tid = threadIdx.x;
    const int l   = tid & 63, w = tid >> 6;
    const int g   = l >> 5;              // half-wave group
    const int p   = l & 31;              // pixel index (C/D col)
    const int py  = p >> 2, pxq = p & 3;
    const int wy  = w >> 1, wx = w & 1;
    const int prow = wy * 8 + py;        // 0..15 tile output row
    const int sx   = wx * 4 + pxq;       // 0..7  tile output col (= slot)
    const int row0 = blockIdx.x * 16;
    const int col0 = blockIdx.y * 8;
    const int b    = blockIdx.z;

    // ---- stage Wc f32 table to LDS (once): 4096 floats = 1024 float4 ----
    {
        const f32x4* src = (const f32x4*)(ws + 65536);
        f32x4* dst = (f32x4*)&wcl[0][0];
#pragma unroll
        for (int k = 0; k < 4; ++k) dst[tid + k * 256] = src[tid + k * 256];
    }
    if (tid == 0) { onev[0] = (f16)1.0f; onev[1] = (f16)0.0f; onev[2] = (f16)0.0f; onev[3] = (f16)0.0f; }

    // ---- x staging map: 144 slot-threads, 4 clamped dword offsets each ----
    const float* xb = x + (size_t)b * FIN * HI * WI;
    int gof0 = 0, gof1 = 0, gof2 = 0, gof3 = 0, lofr = 0, lofs = 0;
    const bool stg = (tid < 144);
    if (stg) {
        int r = tid / 8, s = tid % 8;
        lofr = r; lofs = s;
        int gy = min(row0 + r, HI - 1);
        gof0 = gy * WI + min(col0 + s + 0, WI - 1);
        gof1 = gy * WI + min(col0 + s + 1, WI - 1);
        gof2 = gy * WI + min(col0 + s + 2, WI - 1);
        gof3 = gy * WI + min(col0 + s + 3, WI - 1);
    }

    // stage channel 0 -> buf 0
    if (stg) {
        f16x4 h;
        h[0] = (f16)xb[gof0]; h[1] = (f16)xb[gof1];
        h[2] = (f16)xb[gof2]; h[3] = (f16)xb[gof3];
        *(f16x4*)&xsl[0][lofr][lofs][0] = h;
    }

    // A-fragment prefetch for i=0 (coalesced 16B/lane)
    const uint4* Atab = (const uint4*)ws;
    uint4 Ac0 = Atab[0 * 64 + l];
    uint4 Ac1 = Atab[1 * 64 + l];

    f32x16 acc0 = {}, acc1 = {}, zero = {};

    for (int i = 0; i < FIN; ++i) {
        const int cur = i & 1;

        // issue next-channel x loads + next A-fragments (consume after barrier)
        float v0 = 0, v1 = 0, v2 = 0, v3 = 0;
        if (stg && i + 1 < FIN) {
            const float* xp = xb + (size_t)(i + 1) * (HI * WI);
            v0 = xp[gof0]; v1 = xp[gof1]; v2 = xp[gof2]; v3 = xp[gof3];
        }
        uint4 An0 = Ac0, An1 = Ac1;
        if (i + 1 < FIN) {
            An0 = Atab[((i + 1) * 2 + 0) * 64 + l];
            An1 = Atab[((i + 1) * 2 + 1) * 64 + l];
        }

        __syncthreads();   // xs[cur] writes from previous iteration visible

        // ---- B fragment: j0..3 <- row prow+g; j4..7 <- g? [1,0,0,0] : row prow+2
        f16x4 B1 = *(const f16x4*)&xsl[cur][prow + g][sx][0];
        const f16x4* p2 = g ? (const f16x4*)&onev[0]
                            : (const f16x4*)&xsl[cur][prow + 2][sx][0];
        f16x4 B2 = *p2;
        f16x8 Bf;
#pragma unroll
        for (int c = 0; c < 4; ++c) { Bf[c] = B1[c]; Bf[4 + c] = B2[c]; }

        // ---- Wc quads for this i (f32, broadcast b128 reads per half-wave) ----
        f32x4 wc0[4], wc1[4];
#pragma unroll
        for (int q = 0; q < 4; ++q) {
            wc0[q] = *(const f32x4*)&wcl[i][4 * g + 8 * q];
            wc1[q] = *(const f32x4*)&wcl[i][32 + 4 * g + 8 * q];
        }

        // ---- MFMA: S[o,p] for 2 o-blocks (bias folded via k12) ----
        f16x8 a0 = *(f16x8*)&Ac0;
        f16x8 a1 = *(f16x8*)&Ac1;
        f32x16 S0 = __builtin_amdgcn_mfma_f32_32x32x16_f16(a0, Bf, zero, 0, 0, 0);
        f32x16 S1 = __builtin_amdgcn_mfma_f32_32x32x16_f16(a1, Bf, zero, 0, 0, 0);

        // ---- relu + Wc-weighted accumulate ----
#pragma unroll
        for (int r = 0; r < 16; ++r) {
            float m0 = fmaxf(S0[r], 0.0f);
            float m1 = fmaxf(S1[r], 0.0f);
            acc0[r] = fmaf(wc0[r >> 2][r & 3], m0, acc0[r]);
            acc1[r] = fmaf(wc1[r >> 2][r & 3], m1, acc1[r]);
        }

        // ---- commit staged channel i+1 into the other buffer ----
        if (stg && i + 1 < FIN) {
            f16x4 h;
            h[0] = (f16)v0; h[1] = (f16)v1; h[2] = (f16)v2; h[3] = (f16)v3;
            *(f16x4*)&xsl[cur ^ 1][lofr][lofs][0] = h;
        }
        Ac0 = An0; Ac1 = An1;
    }

    // ---- epilogue: + bc[o], store. lane owns pixel (prow, sx); rows per C/D map
    const int ho = row0 + prow;
    const int wo = col0 + sx;
    if (ho < HO && wo < WO) {
#pragma unroll
        for (int r = 0; r < 16; ++r) {
            int orow = (r & 3) + 8 * (r >> 2) + 4 * g;
            int o0 = orow;        // ob=0
            int o1 = 32 + orow;   // ob=1
            size_t base0 = ((size_t)(b * FOUT + o0) * HO + ho) * WO + wo;
            size_t base1 = ((size_t)(b * FOUT + o1) * HO + ho) * WO + wo;
            out[base0] = acc0[r] + bc[o0];
            out[base1] = acc1[r] + bc[o1];
        }
    }
}

extern "C" void kernel_launch(void* const* d_in, const int* in_sizes, int n_in,
                              void* d_out, int out_size, void* d_ws, size_t ws_size,
                              hipStream_t stream) {
    const float* x  = (const float*)d_in[0];
    const float* Wf = (const float*)d_in[1];
    const float* bf = (const float*)d_in[2];
    const float* Wc = (const float*)d_in[3];
    const float* bc = (const float*)d_in[4];
    float* out = (float*)d_out;
    unsigned short* ws = (unsigned short*)d_ws;

    // build f16 A-fragment + f32 Wc tables in workspace (147,456 B used)
    hipLaunchKernelGGL(prepass, dim3(48), dim3(256), 0, stream, Wf, bf, Wc, ws);

    // 8 row-tiles x 16 col-tiles x 4 batches; 64 o's per block (2 MFMA o-blocks)
    dim3 grid(8, 16, 4);
    hipLaunchKernelGGL(conv_mfma, grid, dim3(256), 0, stream, x, bc, ws, out);
}